// Round 1
// baseline (489.445 us; speedup 1.0000x reference)
//
#include <hip/hip_runtime.h>
#include <hip/hip_bf16.h>
#include <cstdint>

#define NN 8192
#define DIN 512
#define DOUT 128
#define NEG_SLOPE 0.2f
#define MAXE 512

// ---------- Kernel 0: WT[j][k] = W[k][j]  (512x128 -> 128x512) ----------
__global__ void k_transpose_w(const float* __restrict__ W, float* __restrict__ WT) {
    int idx = blockIdx.x * 256 + threadIdx.x;   // 0..65535
    int j = idx >> 9;                            // 0..127
    int k = idx & 511;                           // 0..511
    WT[idx] = W[k * DOUT + j];
}

// ---------- Kernel 1: h = x @ W ; a_s = h@attn_self ; a_n = h@attn_neigh ----
// 256 threads, 16 rows/block, grid = 512 blocks.
// thread: j0 = tid&31 -> cols {j0, j0+32, j0+64, j0+96}; g = tid>>5 -> rows {2g,2g+1}
__global__ __launch_bounds__(256) void k_gemm_h(
    const float* __restrict__ x, const float* __restrict__ WT,
    const float* __restrict__ attn_self, const float* __restrict__ attn_neigh,
    float* __restrict__ h, float* __restrict__ a_s, float* __restrict__ a_n) {
    __shared__ float4 xs[16 * 128];   // 32 KB: [row][k4], identical linear layout to x tile
    const int tid = threadIdx.x;
    const int m0 = blockIdx.x * 16;
    const float4* x4 = (const float4*)(x + (size_t)m0 * DIN);
#pragma unroll
    for (int r = 0; r < 8; ++r) {
        int lin = tid + 256 * r;
        xs[lin] = x4[lin];
    }
    __syncthreads();

    const int j0 = tid & 31;
    const int g = tid >> 5;
    const int r0 = g * 2;
    float acc[2][4] = {};
    const float4* wt0 = (const float4*)WT + (size_t)j0 * 128;  // WT row = 512 floats = 128 float4
    for (int k4 = 0; k4 < 128; ++k4) {
        float4 xa = xs[r0 * 128 + k4];
        float4 xb = xs[(r0 + 1) * 128 + k4];
#pragma unroll
        for (int c = 0; c < 4; ++c) {
            float4 w = wt0[c * 32 * 128 + k4];
            acc[0][c] += xa.x * w.x + xa.y * w.y + xa.z * w.z + xa.w * w.w;
            acc[1][c] += xb.x * w.x + xb.y * w.y + xb.z * w.z + xb.w * w.w;
        }
    }

    float as_c[4], an_c[4];
#pragma unroll
    for (int c = 0; c < 4; ++c) {
        as_c[c] = attn_self[j0 + 32 * c];
        an_c[c] = attn_neigh[j0 + 32 * c];
    }
#pragma unroll
    for (int r = 0; r < 2; ++r) {
        int row = m0 + r0 + r;
        float ps = 0.f, pn = 0.f;
#pragma unroll
        for (int c = 0; c < 4; ++c) {
            h[(size_t)row * DOUT + j0 + 32 * c] = acc[r][c];
            ps += acc[r][c] * as_c[c];
            pn += acc[r][c] * an_c[c];
        }
        // reduce across the 32 lanes holding this row (xor masks <32 stay in half-wave)
#pragma unroll
        for (int off = 16; off > 0; off >>= 1) {
            ps += __shfl_xor(ps, off);
            pn += __shfl_xor(pn, off);
        }
        if (j0 == 0) { a_s[row] = ps; a_n[row] = pn; }
    }
}

// ---------- Kernel 2: per-row sparse attention ----------
// One block (256 thr) per row i: scan adj row (32 KB, coalesced float4),
// build edge list in LDS, softmax over edges, weighted gather of h, relu.
__global__ __launch_bounds__(256) void k_attn(
    const float* __restrict__ adj, const float* __restrict__ h,
    const float* __restrict__ a_s, const float* __restrict__ a_n,
    float* __restrict__ out) {
    const int i = blockIdx.x;
    const int tid = threadIdx.x;
    __shared__ int s_cnt;
    __shared__ int s_idx[MAXE];
    __shared__ float s_w[MAXE];
    __shared__ float s_red[4];
    __shared__ float s_red2[4];
    __shared__ float s_acc[256];
    if (tid == 0) s_cnt = 0;
    __syncthreads();

    // --- scan: 8 independent float4 loads up front (HBM BW) ---
    const float4* arow = (const float4*)(adj + ((size_t)i << 13));
    float4 v[8];
#pragma unroll
    for (int r = 0; r < 8; ++r) v[r] = arow[tid + 256 * r];
#pragma unroll
    for (int r = 0; r < 8; ++r) {
        int base = (tid + 256 * r) * 4;
        if (v[r].x != 0.f) { int p = atomicAdd(&s_cnt, 1); if (p < MAXE) s_idx[p] = base; }
        if (v[r].y != 0.f) { int p = atomicAdd(&s_cnt, 1); if (p < MAXE) s_idx[p] = base + 1; }
        if (v[r].z != 0.f) { int p = atomicAdd(&s_cnt, 1); if (p < MAXE) s_idx[p] = base + 2; }
        if (v[r].w != 0.f) { int p = atomicAdd(&s_cnt, 1); if (p < MAXE) s_idx[p] = base + 3; }
    }
    __syncthreads();
    const int cnt = min(s_cnt, MAXE);   // >=1 (self-loop)
    const float asi = a_s[i];

    // --- logits + max ---
    float m = -1e30f;
    for (int t = tid; t < cnt; t += 256) {
        float e = asi + a_n[s_idx[t]];
        e = (e >= 0.f) ? e : NEG_SLOPE * e;
        s_w[t] = e;
        m = fmaxf(m, e);
    }
#pragma unroll
    for (int off = 32; off > 0; off >>= 1) m = fmaxf(m, __shfl_xor(m, off));
    if ((tid & 63) == 0) s_red[tid >> 6] = m;
    __syncthreads();
    m = fmaxf(fmaxf(s_red[0], s_red[1]), fmaxf(s_red[2], s_red[3]));

    // --- exp + sum ---
    float lsum = 0.f;
    for (int t = tid; t < cnt; t += 256) {
        float w = __expf(s_w[t] - m);
        s_w[t] = w;
        lsum += w;
    }
#pragma unroll
    for (int off = 32; off > 0; off >>= 1) lsum += __shfl_xor(lsum, off);
    if ((tid & 63) == 0) s_red2[tid >> 6] = lsum;
    __syncthreads();
    const float inv_d = 1.0f / (s_red2[0] + s_red2[1] + s_red2[2] + s_red2[3]);

    // --- weighted gather of h rows: col c = tid&127, edges split over 2 halves ---
    const int c = tid & 127;
    const int half = tid >> 7;
    float acc = 0.f;
    int t = half;
    for (; t + 2 < cnt; t += 4) {
        float w0 = s_w[t];     int j0_ = s_idx[t];
        float w1 = s_w[t + 2]; int j1_ = s_idx[t + 2];
        float h0 = h[(size_t)j0_ * DOUT + c];
        float h1 = h[(size_t)j1_ * DOUT + c];
        acc += w0 * h0 + w1 * h1;
    }
    for (; t < cnt; t += 2) acc += s_w[t] * h[(size_t)s_idx[t] * DOUT + c];

    s_acc[tid] = acc;
    __syncthreads();
    if (tid < 128) {
        float tot = (s_acc[tid] + s_acc[tid + 128]) * inv_d;
        out[(size_t)i * DOUT + tid] = fmaxf(tot, 0.f);
    }
}

extern "C" void kernel_launch(void* const* d_in, const int* in_sizes, int n_in,
                              void* d_out, int out_size, void* d_ws, size_t ws_size,
                              hipStream_t stream) {
    const float* x          = (const float*)d_in[0];
    const float* adj        = (const float*)d_in[1];
    const float* W          = (const float*)d_in[2];
    const float* attn_self  = (const float*)d_in[3];
    const float* attn_neigh = (const float*)d_in[4];
    float* out = (float*)d_out;

    // workspace layout (floats): WT[65536] | h[8192*128] | a_s[8192] | a_n[8192]
    float* WT  = (float*)d_ws;
    float* h   = WT + 65536;
    float* a_s = h + (size_t)NN * DOUT;
    float* a_n = a_s + NN;

    hipLaunchKernelGGL(k_transpose_w, dim3(256), dim3(256), 0, stream, W, WT);
    hipLaunchKernelGGL(k_gemm_h, dim3(NN / 16), dim3(256), 0, stream,
                       x, WT, attn_self, attn_neigh, h, a_s, a_n);
    hipLaunchKernelGGL(k_attn, dim3(NN), dim3(256), 0, stream, adj, h, a_s, a_n, out);
}

// Round 3
// 423.377 us; speedup vs baseline: 1.1561x; 1.1561x over previous
//
#include <hip/hip_runtime.h>
#include <hip/hip_bf16.h>
#include <cstdint>

#define NN 8192
#define DIN 512
#define DOUT 128
#define NEG_SLOPE 0.2f
#define MAXE 256

typedef float fvec4 __attribute__((ext_vector_type(4)));

__device__ inline fvec4 ntload4(const float* p) {
#if __has_builtin(__builtin_nontemporal_load)
    return __builtin_nontemporal_load((const fvec4*)p);
#else
    return *(const fvec4*)p;
#endif
}

// ---------- Kernel 1: h = x @ W ; a_s = h@attn_self ; a_n = h@attn_neigh ----
// 256 threads, 8 rows/block, 1024 blocks (4/CU). Thread = (c4 = tid&31 ->
// cols 4*c4..4*c4+3, rg = tid>>5 -> row rg). W loads are lane-contiguous
// (coalesced, L2-broadcast across blocks) -- no transpose needed.
__global__ __launch_bounds__(256) void k_gemm_h(
    const float* __restrict__ x, const float* __restrict__ W,
    const float* __restrict__ attn_self, const float* __restrict__ attn_neigh,
    float* __restrict__ h, float* __restrict__ a_s, float* __restrict__ a_n) {
    __shared__ float4 xs[8 * 128];   // 8 rows x 512 floats = 16 KB
    const int tid = threadIdx.x;
    const int m0 = blockIdx.x * 8;
    const float4* x4 = (const float4*)(x + (size_t)m0 * DIN);
#pragma unroll
    for (int r = 0; r < 4; ++r) xs[tid + 256 * r] = x4[tid + 256 * r];
    __syncthreads();

    const int c4 = tid & 31;
    const int rg = tid >> 5;
    const float4* W4 = (const float4*)W;      // row k = 32 float4
    const float4* xr = xs + rg * 128;
    float4 acc = {0.f, 0.f, 0.f, 0.f};
#pragma unroll 4
    for (int k4 = 0; k4 < 128; ++k4) {
        float4 xv = xr[k4];
        float4 w0 = W4[(4 * k4 + 0) * 32 + c4];
        float4 w1 = W4[(4 * k4 + 1) * 32 + c4];
        float4 w2 = W4[(4 * k4 + 2) * 32 + c4];
        float4 w3 = W4[(4 * k4 + 3) * 32 + c4];
        acc.x += xv.x * w0.x + xv.y * w1.x + xv.z * w2.x + xv.w * w3.x;
        acc.y += xv.x * w0.y + xv.y * w1.y + xv.z * w2.y + xv.w * w3.y;
        acc.z += xv.x * w0.z + xv.y * w1.z + xv.z * w2.z + xv.w * w3.z;
        acc.w += xv.x * w0.w + xv.y * w1.w + xv.z * w2.w + xv.w * w3.w;
    }
    const int row = m0 + rg;
    ((float4*)h)[(size_t)row * 32 + c4] = acc;

    float4 as4 = ((const float4*)attn_self)[c4];
    float4 an4 = ((const float4*)attn_neigh)[c4];
    float ps = acc.x * as4.x + acc.y * as4.y + acc.z * as4.z + acc.w * as4.w;
    float pn = acc.x * an4.x + acc.y * an4.y + acc.z * an4.z + acc.w * an4.w;
#pragma unroll
    for (int off = 16; off > 0; off >>= 1) {
        ps += __shfl_xor(ps, off);
        pn += __shfl_xor(pn, off);
    }
    if (c4 == 0) { a_s[row] = ps; a_n[row] = pn; }
}

// ---------- Kernel 2: per-row sparse attention ----------
// One block (256 thr) per row i. Single pass: scan adj row (nontemporal
// float4, coalesced), compute leaky logit inline for each edge, LDS edge
// list, softmax over edges, weighted gather of h, relu.
__global__ __launch_bounds__(256) void k_attn(
    const float* __restrict__ adj, const float* __restrict__ h,
    const float* __restrict__ a_s, const float* __restrict__ a_n,
    float* __restrict__ out) {
    const int i = blockIdx.x;
    const int tid = threadIdx.x;
    __shared__ int s_cnt;
    __shared__ int s_idx[MAXE];
    __shared__ float s_w[MAXE];     // logits, then exp weights in-place
    __shared__ float s_red[4];
    __shared__ float s_red2[4];
    __shared__ float s_acc[256];
    if (tid == 0) s_cnt = 0;
    const float asi = a_s[i];
    __syncthreads();

    // --- scan + inline logits ---
    const float* arow = adj + ((size_t)i << 13);
    fvec4 v[8];
#pragma unroll
    for (int r = 0; r < 8; ++r) v[r] = ntload4(arow + 4 * (tid + 256 * r));
#pragma unroll
    for (int r = 0; r < 8; ++r) {
        int base = (tid + 256 * r) * 4;
#pragma unroll
        for (int q = 0; q < 4; ++q) {
            if (v[r][q] != 0.f) {
                int j = base + q;
                float e = asi + a_n[j];
                e = (e >= 0.f) ? e : NEG_SLOPE * e;
                int p = atomicAdd(&s_cnt, 1);
                if (p < MAXE) { s_idx[p] = j; s_w[p] = e; }
            }
        }
    }
    __syncthreads();
    const int cnt = min(s_cnt, MAXE);   // >=1 (self-loop)

    // --- max ---
    float m = -1e30f;
    for (int t = tid; t < cnt; t += 256) m = fmaxf(m, s_w[t]);
#pragma unroll
    for (int off = 32; off > 0; off >>= 1) m = fmaxf(m, __shfl_xor(m, off));
    if ((tid & 63) == 0) s_red[tid >> 6] = m;
    __syncthreads();
    m = fmaxf(fmaxf(s_red[0], s_red[1]), fmaxf(s_red[2], s_red[3]));

    // --- exp + sum (in-place) ---
    float lsum = 0.f;
    for (int t = tid; t < cnt; t += 256) {
        float w = __expf(s_w[t] - m);
        s_w[t] = w;
        lsum += w;
    }
#pragma unroll
    for (int off = 32; off > 0; off >>= 1) lsum += __shfl_xor(lsum, off);
    if ((tid & 63) == 0) s_red2[tid >> 6] = lsum;
    __syncthreads();
    const float inv_d = 1.0f / (s_red2[0] + s_red2[1] + s_red2[2] + s_red2[3]);

    // --- weighted gather: col c = tid&127, edges interleaved over 2 halves,
    //     4 loads in flight per thread ---
    const int c = tid & 127;
    const int half = tid >> 7;
    float acc = 0.f;
    int t = half;
    for (; t + 6 < cnt; t += 8) {
        float w0 = s_w[t];     int j0 = s_idx[t];
        float w1 = s_w[t + 2]; int j1 = s_idx[t + 2];
        float w2 = s_w[t + 4]; int j2 = s_idx[t + 4];
        float w3 = s_w[t + 6]; int j3 = s_idx[t + 6];
        float h0 = h[(size_t)j0 * DOUT + c];
        float h1 = h[(size_t)j1 * DOUT + c];
        float h2 = h[(size_t)j2 * DOUT + c];
        float h3 = h[(size_t)j3 * DOUT + c];
        acc += w0 * h0 + w1 * h1 + w2 * h2 + w3 * h3;
    }
    for (; t < cnt; t += 2) acc += s_w[t] * h[(size_t)s_idx[t] * DOUT + c];

    s_acc[tid] = acc;
    __syncthreads();
    if (tid < 128) {
        float tot = (s_acc[tid] + s_acc[tid + 128]) * inv_d;
        out[(size_t)i * DOUT + tid] = fmaxf(tot, 0.f);
    }
}

extern "C" void kernel_launch(void* const* d_in, const int* in_sizes, int n_in,
                              void* d_out, int out_size, void* d_ws, size_t ws_size,
                              hipStream_t stream) {
    const float* x          = (const float*)d_in[0];
    const float* adj        = (const float*)d_in[1];
    const float* W          = (const float*)d_in[2];
    const float* attn_self  = (const float*)d_in[3];
    const float* attn_neigh = (const float*)d_in[4];
    float* out = (float*)d_out;

    // workspace layout (floats): h[8192*128] | a_s[8192] | a_n[8192]
    float* h   = (float*)d_ws;
    float* a_s = h + (size_t)NN * DOUT;
    float* a_n = a_s + NN;

    hipLaunchKernelGGL(k_gemm_h, dim3(NN / 8), dim3(256), 0, stream,
                       x, W, attn_self, attn_neigh, h, a_s, a_n);
    hipLaunchKernelGGL(k_attn, dim3(NN), dim3(256), 0, stream, adj, h, a_s, a_n, out);
}